// Round 4
// baseline (170.285 us; speedup 1.0000x reference)
//
#include <hip/hip_runtime.h>

// Problem constants: B=8, N_IN=256, N=8192, D=64, K=512
#define NIN    256
#define NCOL   8192
#define DDIM   64
#define KCODES 512
#define NCTOT  65536                         // total columns = B*N
#define ZQ_ELEMS (8ull * 64ull * 8192ull)    // zq floats; hist follows

// ---------------------------------------------------------------------------
// K1 prep: Wt[i][d] = W[d][i]; emb_sq[k] = ||emb[k]||^2 (ascending-d, same as
// rounds 1-3); hist_out = ind_hist; cand[c] = ~0 (u64 argmin accumulator).
// Re-runs every call: deterministic under graph replay.
// ---------------------------------------------------------------------------
__global__ __launch_bounds__(256) void vq_prep(const float* __restrict__ W,
                                               const float* __restrict__ emb,
                                               const float* __restrict__ ind_hist,
                                               float* __restrict__ Wt,
                                               float* __restrict__ emb_sq,
                                               unsigned long long* __restrict__ cand,
                                               float* __restrict__ hist_out)
{
    int t = blockIdx.x * 256 + threadIdx.x;   // grid = 256 blocks -> t < 65536
    cand[t] = ~0ull;
    if (t < NIN * DDIM) {
        int i = t >> 6;
        int d = t & 63;
        Wt[t] = W[d * NIN + i];
    }
    if (t < KCODES) {
        const float* __restrict__ ek = emb + t * DDIM;
        float s = 0.f;
        #pragma unroll
        for (int d = 0; d < DDIM; ++d) s = fmaf(ek[d], ek[d], s);
        emb_sq[t] = s;
        hist_out[t] = ind_hist[t];
    }
}

// ---------------------------------------------------------------------------
// K2 conv: 1024 blocks x 256. Wave w computes d-slice [16w,16w+16) for 64
// cols (lane=col). Ascending-i fmaf chain (bit-identical ze to rounds 1-3).
// Writes ze straight to the OUTPUT buffer in (b,d,n) layout — coalesced;
// vq_final overwrites it with zq later.
// ---------------------------------------------------------------------------
__global__ __launch_bounds__(256, 4) void vq_conv(const float* __restrict__ z,
                                                  const float* __restrict__ Wt,
                                                  float* __restrict__ out)
{
    const int tid = threadIdx.x;
    const int cl  = tid & 63;
    const int w   = __builtin_amdgcn_readfirstlane(tid >> 6);
    const int C   = blockIdx.x * 64 + cl;
    const int b   = C >> 13;
    const int n   = C & (NCOL - 1);

    const float* __restrict__ zp = z + (size_t)b * NIN * NCOL + n;
    const float* __restrict__ wp = Wt + w * 16;

    float acc[16];
    #pragma unroll
    for (int j = 0; j < 16; ++j) acc[j] = 0.f;

    for (int i = 0; i < NIN; i += 4) {
        float z0 = zp[(size_t)(i + 0) * NCOL];
        float z1 = zp[(size_t)(i + 1) * NCOL];
        float z2 = zp[(size_t)(i + 2) * NCOL];
        float z3 = zp[(size_t)(i + 3) * NCOL];
        const float* __restrict__ w0 = wp + (size_t)(i + 0) * DDIM;  // s_load
        const float* __restrict__ w1 = wp + (size_t)(i + 1) * DDIM;
        const float* __restrict__ w2 = wp + (size_t)(i + 2) * DDIM;
        const float* __restrict__ w3 = wp + (size_t)(i + 3) * DDIM;
        #pragma unroll
        for (int j = 0; j < 16; ++j) {
            float a = acc[j];
            a = fmaf(w0[j], z0, a);   // ascending i: bit-exact vs rounds 1-3
            a = fmaf(w1[j], z1, a);
            a = fmaf(w2[j], z2, a);
            a = fmaf(w3[j], z3, a);
            acc[j] = a;
        }
    }

    float* __restrict__ op = out + ((size_t)b * DDIM + w * 16) * NCOL + n;
    #pragma unroll
    for (int j = 0; j < 16; ++j) op[(size_t)j * NCOL] = acc[j];
}

// ---------------------------------------------------------------------------
// K3 search: 2048 blocks x 256, NO launch cap (VGPR ~85 -> 5-6 waves/SIMD).
// Block = 64 cols x k-half; wave w scans k in [256*(bx&1)+64w, +64).
// ze tile coop-loaded (coalesced) -> LDS -> per-lane regs; zesq recomputed
// per thread with the same ascending-d chain (bit-exact). Candidate folded
// into global u64 atomicMin: hi = order-preserving dist bits, lo = k, so
// lexicographic min == first-min-k argmin. Commutative -> deterministic.
// ---------------------------------------------------------------------------
__global__ __launch_bounds__(256) void vq_search(const float* __restrict__ zeb,
                                                 const float* __restrict__ emb,
                                                 const float* __restrict__ emb_sq,
                                                 unsigned long long* __restrict__ cand)
{
    __shared__ float ze_lds[64][DDIM + 4];   // stride 68

    const int tid   = threadIdx.x;
    const int C0    = (blockIdx.x >> 1) * 64;
    const int khalf = blockIdx.x & 1;
    const int b     = C0 >> 13;              // 64-col tile never crosses b
    const int n0    = C0 & (NCOL - 1);

    // coop load ze tile from out buffer (b,d,n): thread t -> d-row r, 16 cols
    {
        const int r  = tid >> 2;
        const int cc = (tid & 3) * 16;
        const float4* __restrict__ src = reinterpret_cast<const float4*>(
            zeb + ((size_t)b * DDIM + r) * NCOL + n0 + cc);
        #pragma unroll
        for (int v = 0; v < 4; ++v) {
            float4 x = src[v];
            ze_lds[cc + 4 * v + 0][r] = x.x;
            ze_lds[cc + 4 * v + 1][r] = x.y;
            ze_lds[cc + 4 * v + 2][r] = x.z;
            ze_lds[cc + 4 * v + 3][r] = x.w;
        }
    }
    __syncthreads();

    const int lane = tid & 63;
    const int w    = __builtin_amdgcn_readfirstlane(tid >> 6);

    float ze[DDIM];
    #pragma unroll
    for (int q = 0; q < DDIM / 4; ++q) {
        float4 v = *reinterpret_cast<const float4*>(&ze_lds[lane][4 * q]);
        ze[4 * q + 0] = v.x;
        ze[4 * q + 1] = v.y;
        ze[4 * q + 2] = v.z;
        ze[4 * q + 3] = v.w;
    }

    float zesq = 0.f;                        // same ascending chain as before
    #pragma unroll
    for (int d = 0; d < DDIM; ++d) zesq = fmaf(ze[d], ze[d], zesq);

    const int k0 = khalf * (KCODES / 2) + w * 64;
    float best  = 3.4e38f;
    int   bestk = k0;
    for (int kk = 0; kk < 64; ++kk) {
        const int k = k0 + kk;
        const float* __restrict__ ek = emb + (size_t)k * DDIM;   // s_load
        float cr = 0.f;
        #pragma unroll
        for (int d = 0; d < DDIM; ++d) cr = fmaf(ek[d], ze[d], cr);
        float dist = (zesq + emb_sq[k]) - 2.0f * cr;   // ref formula order
        if (dist < best) { best = dist; bestk = k; }   // first-min tie-break
    }

    unsigned u   = __float_as_uint(best);
    unsigned enc = u ^ ((unsigned)((int)u >> 31) | 0x80000000u);  // order-map
    unsigned long long pk =
        ((unsigned long long)enc << 32) | (unsigned)bestk;
    atomicMin(&cand[C0 + lane], pk);
}

// ---------------------------------------------------------------------------
// K4 final: 1024 blocks x 256. Re-stage ze tile (same coop load), read the
// winning (dist,k), write zq = ze + (emb[k]-ze) coalesced, 1 hist atomic/col.
// ---------------------------------------------------------------------------
__global__ __launch_bounds__(256, 4) void vq_final(const float* __restrict__ emb,
                                                   const unsigned long long* __restrict__ cand,
                                                   float* __restrict__ out,
                                                   float* __restrict__ hist)
{
    __shared__ float ze_lds[64][DDIM + 4];

    const int tid = threadIdx.x;
    const int C0  = blockIdx.x * 64;
    const int b   = C0 >> 13;
    const int n0  = C0 & (NCOL - 1);

    {
        const int r  = tid >> 2;
        const int cc = (tid & 3) * 16;
        const float4* __restrict__ src = reinterpret_cast<const float4*>(
            out + ((size_t)b * DDIM + r) * NCOL + n0 + cc);
        #pragma unroll
        for (int v = 0; v < 4; ++v) {
            float4 x = src[v];
            ze_lds[cc + 4 * v + 0][r] = x.x;
            ze_lds[cc + 4 * v + 1][r] = x.y;
            ze_lds[cc + 4 * v + 2][r] = x.z;
            ze_lds[cc + 4 * v + 3][r] = x.w;
        }
    }
    __syncthreads();

    const int lane = tid & 63;
    const int w    = __builtin_amdgcn_readfirstlane(tid >> 6);
    const int C    = C0 + lane;
    const int n    = n0 + lane;

    const int fk = (int)(unsigned)cand[C];
    if (w == 0) atomicAdd(hist + fk, 1.0f);

    const float4* __restrict__ eb =
        reinterpret_cast<const float4*>(emb + (size_t)fk * DDIM) + w * 4;
    float* __restrict__ op = out + ((size_t)b * DDIM + w * 16) * NCOL + n;
    #pragma unroll
    for (int v = 0; v < 4; ++v) {
        float4 e = eb[v];
        float z0 = ze_lds[lane][w * 16 + 4 * v + 0];
        float z1 = ze_lds[lane][w * 16 + 4 * v + 1];
        float z2 = ze_lds[lane][w * 16 + 4 * v + 2];
        float z3 = ze_lds[lane][w * 16 + 4 * v + 3];
        op[(size_t)(4 * v + 0) * NCOL] = z0 + (e.x - z0);
        op[(size_t)(4 * v + 1) * NCOL] = z1 + (e.y - z1);
        op[(size_t)(4 * v + 2) * NCOL] = z2 + (e.z - z2);
        op[(size_t)(4 * v + 3) * NCOL] = z3 + (e.w - z3);
    }
}

// ---------------------------------------------------------------------------
extern "C" void kernel_launch(void* const* d_in, const int* in_sizes, int n_in,
                              void* d_out, int out_size, void* d_ws, size_t ws_size,
                              hipStream_t stream)
{
    const float* z        = (const float*)d_in[0];  // (8, 256, 8192)
    const float* W        = (const float*)d_in[1];  // (64, 256)
    const float* emb      = (const float*)d_in[2];  // (512, 64)
    const float* ind_hist = (const float*)d_in[3];  // (512,)

    float* out  = (float*)d_out;                    // zq then hist
    float* hist = out + ZQ_ELEMS;

    unsigned long long* cand = (unsigned long long*)d_ws;          // 512 KB
    float* Wt     = (float*)((char*)d_ws + NCTOT * 8);             // 64 KB
    float* emb_sq = Wt + NIN * DDIM;                               // 2 KB

    hipLaunchKernelGGL(vq_prep, dim3(NCTOT / 256), dim3(256), 0, stream,
                       W, emb, ind_hist, Wt, emb_sq, cand, hist);

    hipLaunchKernelGGL(vq_conv, dim3(1024), dim3(256), 0, stream,
                       z, Wt, out);

    hipLaunchKernelGGL(vq_search, dim3(2048), dim3(256), 0, stream,
                       out, emb, emb_sq, cand);

    hipLaunchKernelGGL(vq_final, dim3(1024), dim3(256), 0, stream,
                       emb, cand, out, hist);
}

// Round 5
// 123.738 us; speedup vs baseline: 1.3762x; 1.3762x over previous
//
#include <hip/hip_runtime.h>

// Problem constants: B=8, N_IN=256, N=8192, D=64, K=512
#define NIN    256
#define NCOL   8192
#define DDIM   64
#define KCODES 512
#define ZQ_ELEMS (8ull * 64ull * 8192ull)    // zq floats; hist follows

// ---------------------------------------------------------------------------
// Prep: Wt[i][d] = W[d][i] (conv s_loads contiguous); embT[d][k] = emb[k][d]
// (search s_loads contiguous in k); emb_sq[k] = ||emb[k]||^2 (ascending-d,
// bit-exact vs all prior rounds); hist_out = ind_hist (re-init every call).
// Grid: 128 blocks x 256 = 32768 threads.
// ---------------------------------------------------------------------------
__global__ __launch_bounds__(256) void vq_prep(const float* __restrict__ W,
                                               const float* __restrict__ emb,
                                               const float* __restrict__ ind_hist,
                                               float* __restrict__ Wt,
                                               float* __restrict__ embT,
                                               float* __restrict__ emb_sq,
                                               float* __restrict__ hist_out)
{
    const int t = blockIdx.x * 256 + threadIdx.x;   // t < 32768
    if (t < NIN * DDIM) {
        int i = t >> 6;
        int d = t & 63;
        Wt[t] = W[d * NIN + i];
    }
    {
        int d = t >> 9;          // 0..63
        int k = t & 511;         // 0..511
        embT[t] = emb[k * DDIM + d];
    }
    if (t < KCODES) {
        const float* __restrict__ ek = emb + t * DDIM;
        float s = 0.f;
        #pragma unroll
        for (int d = 0; d < DDIM; ++d) s = fmaf(ek[d], ek[d], s);
        emb_sq[t] = s;
        hist_out[t] = ind_hist[t];
    }
}

// ---------------------------------------------------------------------------
// Main fused kernel: block (256 thr / 4 waves) owns 64 columns.
//  conv   : wave w computes d-slice [16w,16w+16) for 64 cols (lane=col,
//           Wt s_load, ascending-i fmaf — bit-identical to rounds 1-4).
//           Stores to LDS tile ze_lds[col][d], stride 65 (odd: conflict-free
//           b32 access both phases).
//  search : wave w owns k-quarter [128w,128w+128), tiled K_t=32.
//           Per d: ONE ds_read_b32 (ze[cl][d]) -> 32 FMAs with wave-uniform
//           embT[d][k..k+31] (s_load_dwordx16 x2). 0.125 B LDS per FMA
//           (32x less than round 3/4 — that was the bottleneck).
//           dist = (zesq + emb_sq[k]) - 2*cr, ascending-d cr: bit-exact.
//  merge  : 4 per-wave candidates via LDS, ascending-w strict-< scan
//           == jnp.argmin first-min tie-break.
//  epilog : wave w writes zq d-slice [16w,16w+16); 1 hist atomic per column.
// ---------------------------------------------------------------------------
__global__ __launch_bounds__(256, 4) void vq_main(const float* __restrict__ z,
                                                  const float* __restrict__ Wt,
                                                  const float* __restrict__ emb,
                                                  const float* __restrict__ embT,
                                                  const float* __restrict__ emb_sq,
                                                  float* __restrict__ out,
                                                  float* __restrict__ hist)
{
    __shared__ float ze_lds[64][DDIM + 1];   // stride 65: odd -> 2-way free
    __shared__ float bw_lds[4][64];
    __shared__ int   bk_lds[4][64];

    const int tid = threadIdx.x;
    const int cl  = tid & 63;                                   // column (lane)
    const int w   = __builtin_amdgcn_readfirstlane(tid >> 6);   // wave id 0..3
    const int C   = blockIdx.x * 64 + cl;
    const int b   = C >> 13;
    const int n   = C & (NCOL - 1);

    // ---------------- conv phase (verified round-4 code, LDS sink) --------
    {
        const float* __restrict__ zp = z + (size_t)b * NIN * NCOL + n;
        const float* __restrict__ wp = Wt + w * 16;

        float acc[16];
        #pragma unroll
        for (int j = 0; j < 16; ++j) acc[j] = 0.f;

        for (int i = 0; i < NIN; i += 4) {
            float z0 = zp[(size_t)(i + 0) * NCOL];
            float z1 = zp[(size_t)(i + 1) * NCOL];
            float z2 = zp[(size_t)(i + 2) * NCOL];
            float z3 = zp[(size_t)(i + 3) * NCOL];
            const float* __restrict__ w0 = wp + (size_t)(i + 0) * DDIM;  // s_load
            const float* __restrict__ w1 = wp + (size_t)(i + 1) * DDIM;
            const float* __restrict__ w2 = wp + (size_t)(i + 2) * DDIM;
            const float* __restrict__ w3 = wp + (size_t)(i + 3) * DDIM;
            #pragma unroll
            for (int j = 0; j < 16; ++j) {
                float a = acc[j];
                a = fmaf(w0[j], z0, a);   // ascending i: bit-exact
                a = fmaf(w1[j], z1, a);
                a = fmaf(w2[j], z2, a);
                a = fmaf(w3[j], z3, a);
                acc[j] = a;
            }
        }
        #pragma unroll
        for (int j = 0; j < 16; ++j) ze_lds[cl][w * 16 + j] = acc[j];
    }
    __syncthreads();

    // ---------------- zesq: ascending-d chain (bit-exact) -----------------
    float zesq = 0.f;
    #pragma unroll 4
    for (int d = 0; d < DDIM; ++d) {
        float zd = ze_lds[cl][d];
        zesq = fmaf(zd, zd, zesq);
    }

    // ---------------- search: wave w owns k in [128w, 128w+128) -----------
    const int k0 = w * (KCODES / 4);
    float best  = 3.4e38f;
    int   bestk = k0;

    for (int t4 = 0; t4 < 4; ++t4) {                  // 4 k-tiles of 32
        const int kt = k0 + t4 * 32;
        const float* __restrict__ ep0 = embT + kt;    // + d*512 per step

        float acc[32];
        #pragma unroll
        for (int kk = 0; kk < 32; ++kk) acc[kk] = 0.f;

        #pragma unroll 2
        for (int d = 0; d < DDIM; ++d) {
            float zd = ze_lds[cl][d];                 // 1 ds_read -> 32 FMAs
            const float* __restrict__ ep = ep0 + (size_t)d * KCODES; // s_load x16
            #pragma unroll
            for (int kk = 0; kk < 32; ++kk)
                acc[kk] = fmaf(ep[kk], zd, acc[kk]);  // ascending d per (c,k)
        }

        #pragma unroll
        for (int kk = 0; kk < 32; ++kk) {
            const int k = kt + kk;
            float dist = (zesq + emb_sq[k]) - 2.0f * acc[kk];  // ref order
            if (dist < best) { best = dist; bestk = k; }       // first-min
        }
    }
    bw_lds[w][cl] = best;
    bk_lds[w][cl] = bestk;
    __syncthreads();

    // ---------------- merge 4 candidates (ascending w, strict <) ----------
    float fb = bw_lds[0][cl];
    int   fk = bk_lds[0][cl];
    #pragma unroll
    for (int ww = 1; ww < 4; ++ww) {
        float v = bw_lds[ww][cl];
        int  kv = bk_lds[ww][cl];
        if (v < fb) { fb = v; fk = kv; }
    }

    // ---------------- histogram: one atomic per column --------------------
    if (w == 0) atomicAdd(hist + fk, 1.0f);

    // ---------------- straight-through output: wave w writes its d-slice --
    const float4* __restrict__ eb =
        reinterpret_cast<const float4*>(emb + (size_t)fk * DDIM) + w * 4;
    float* __restrict__ op = out + ((size_t)b * DDIM + w * 16) * NCOL + n;
    #pragma unroll
    for (int v = 0; v < 4; ++v) {
        float4 e = eb[v];
        float z0 = ze_lds[cl][w * 16 + 4 * v + 0];
        float z1 = ze_lds[cl][w * 16 + 4 * v + 1];
        float z2 = ze_lds[cl][w * 16 + 4 * v + 2];
        float z3 = ze_lds[cl][w * 16 + 4 * v + 3];
        op[(size_t)(4 * v + 0) * NCOL] = z0 + (e.x - z0);
        op[(size_t)(4 * v + 1) * NCOL] = z1 + (e.y - z1);
        op[(size_t)(4 * v + 2) * NCOL] = z2 + (e.z - z2);
        op[(size_t)(4 * v + 3) * NCOL] = z3 + (e.w - z3);
    }
}

// ---------------------------------------------------------------------------
extern "C" void kernel_launch(void* const* d_in, const int* in_sizes, int n_in,
                              void* d_out, int out_size, void* d_ws, size_t ws_size,
                              hipStream_t stream)
{
    const float* z        = (const float*)d_in[0];  // (8, 256, 8192)
    const float* W        = (const float*)d_in[1];  // (64, 256)
    const float* emb      = (const float*)d_in[2];  // (512, 64)
    const float* ind_hist = (const float*)d_in[3];  // (512,)

    float* out  = (float*)d_out;                    // zq then hist
    float* hist = out + ZQ_ELEMS;

    float* Wt     = (float*)d_ws;                   // 16384 floats
    float* embT   = Wt + NIN * DDIM;                // 32768 floats
    float* emb_sq = embT + DDIM * KCODES;           // 512 floats

    hipLaunchKernelGGL(vq_prep, dim3(128), dim3(256), 0, stream,
                       W, emb, ind_hist, Wt, embT, emb_sq, hist);

    // 64 columns per block -> 1024 blocks of 256
    hipLaunchKernelGGL(vq_main, dim3(1024), dim3(256), 0, stream,
                       z, Wt, emb, embT, emb_sq, out, hist);
}